// Round 11
// baseline (7777.914 us; speedup 1.0000x reference)
//
#include <hip/hip_runtime.h>
#include <math.h>

// Problem constants (Elman RNN)
#define TT 4096
#define HH 2048
#define OO 512

#define NB  128    // scan blocks
#define RPB 16     // rows per block = HH/NB
#define MBW (HH/2) // mailbox words per buffer (fp16 x2 per word)

#define CHUNK_T 64             // t-rows per xp chunk
#define NCHUNK  (TT/CHUNK_T)   // 64 chunks
#define HTILE   128
#define NHT     (HH/HTILE)     // 16 h-tiles per chunk

typedef __fp16 half2v __attribute__((ext_vector_type(2)));

// ---------------------------------------------------------------------------
// R11 FUSED kernel: ALL THREE PHASES in one dispatch.
//   blocks 0..127   : scan; ALSO computes out[t-1] = W_lin h_{t-1} + b_lin
//                     in-step (full h_{t-1} is already in LDS!) -- the
//                     trailing phase-3 GEMM dispatch (~345us) is deleted.
//   blocks 128..255 : phase-1 xp GEMM workers (unchanged from R10).
//
// out-projection mapping (scan block b owns out cols 4b..4b+3):
//   thread (wave,lane): r=lane&15, q=lane>>4, o=lane&3, jp=(lane>>2)&3
//   covers h[k], k = wave*128 + (2jp+u)*16 + q*4 + i (u<2,i<4): 8 wl weights.
//   po folds over lane bits 2..5 (shfl_xor 4,8,16,32) -> lanes 0..3 hold
//   wave-partials -> outp[t&1][wave*4+o] (parity dbuf = provably race-free:
//   overwrite at t+2 is gated by wave0's t+2 publish which follows the read).
//   wave0: reads outp BEFORE publish (value secured), folds+stores AFTER
//   publish -- off the critical path.
// ---------------------------------------------------------------------------
__global__ __launch_bounds__(1024) void rnn_fused(
    const float* __restrict__ x,     // (T,H) input
    const float* __restrict__ Wih,   // (H,H)
    const float* __restrict__ bih,   // (H)
    const float* __restrict__ Whh,   // (H,H)
    const float* __restrict__ bhh,   // (H)
    const float* __restrict__ h0,    // (H)
    const float* __restrict__ Wlin,  // (O,H)
    const float* __restrict__ blin,  // (O)
    float* __restrict__ xp,          // (T,H) workspace: input projection
    float* __restrict__ out,         // (T,O) final output
    unsigned long long* __restrict__ mbox,  // [2][MBW] tagged fp16x2 mailbox
    int* __restrict__ chunk_done)    // [NCHUNK] xp-chunk arm counters
{
    const int tid = threadIdx.x;     // 0..1023

    if (blockIdx.x >= NB) {
        // ------------------- xp GEMM worker (unchanged R10) -------------------
        __shared__ float As[16][65];     // [kk][t-row], padded
        __shared__ float Bs[16][132];    // [kk][h-col], padded+aligned

        const int w2   = blockIdx.x - NB;   // 0..127
        const int ty   = tid >> 5;          // 0..31 -> t-rows ty*2, ty*2+1
        const int tx   = tid & 31;          // 0..31 -> h-cols tx*4..
        const int arow = tid >> 4;          // 0..63
        const int akk  = tid & 15;
        const int bcol = tid >> 3;          // 0..127
        const int bkk  = (tid & 7) * 2;

        for (int round = 0; round < (NCHUNK * NHT) / 128; ++round) {
            const int tile  = w2 + 128 * round;   // t-major: early t first
            const int chunk = tile >> 4;
            const int htile = tile & 15;
            const int bm = chunk * CHUNK_T;
            const int bn = htile * HTILE;

            float acc[2][4];
#pragma unroll
            for (int i = 0; i < 2; ++i)
#pragma unroll
                for (int j = 0; j < 4; ++j) acc[i][j] = 0.f;

            for (int k0 = 0; k0 < HH; k0 += 16) {
                float  av = x[(size_t)(bm + arow) * HH + k0 + akk];
                float2 bv = *(const float2*)&Wih[(size_t)(bn + bcol) * HH + k0 + bkk];
                __syncthreads();
                As[akk][arow]     = av;
                Bs[bkk][bcol]     = bv.x;
                Bs[bkk + 1][bcol] = bv.y;
                __syncthreads();
#pragma unroll
                for (int kk = 0; kk < 16; ++kk) {
                    float a0 = As[kk][ty * 2];
                    float a1 = As[kk][ty * 2 + 1];
                    float b0 = Bs[kk][tx * 4 + 0];
                    float b1 = Bs[kk][tx * 4 + 1];
                    float b2 = Bs[kk][tx * 4 + 2];
                    float b3 = Bs[kk][tx * 4 + 3];
                    acc[0][0] += a0 * b0; acc[0][1] += a0 * b1;
                    acc[0][2] += a0 * b2; acc[0][3] += a0 * b3;
                    acc[1][0] += a1 * b0; acc[1][1] += a1 * b1;
                    acc[1][2] += a1 * b2; acc[1][3] += a1 * b3;
                }
            }
#pragma unroll
            for (int i = 0; i < 2; ++i) {
                const int m = bm + ty * 2 + i;
#pragma unroll
                for (int j = 0; j < 4; ++j) {
                    const int n = bn + tx * 4 + j;
                    __hip_atomic_store(&xp[(size_t)m * HH + n],
                                       acc[i][j] + bih[n],
                                       __ATOMIC_RELAXED, __HIP_MEMORY_SCOPE_AGENT);
                }
            }
            __syncthreads();   // all waves' stores retired first
            if (tid == 0)
                __hip_atomic_fetch_add(&chunk_done[chunk], 1,
                                       __ATOMIC_RELEASE, __HIP_MEMORY_SCOPE_AGENT);
        }
        return;
    }

    // ------------------------- scan + out projection -----------------------
    const int b    = blockIdx.x;     // 0..127
    const int wave = tid >> 6;       // 0..15
    const int lane = tid & 63;
    const int r    = lane & 15;      // local row 0..15
    const int q    = lane >> 4;      // 0..3: interleaved 4-float subchunk
    const int row  = b * RPB + r;    // global row this thread accumulates
    const int m0   = wave * 64 + lane;      // my mailbox word (covers 2 rows)
    const int s0   = wave * 128 + 2 * lane; // my 2 floats in hs
    const int o    = lane & 3;              // out column within block
    const int jp   = (lane >> 2) & 3;       // jj-pair for out coverage

    // recurrent weights pinned (atomic loads can't be rematerialized)
    float w[32];
#pragma unroll
    for (int jj = 0; jj < 8; ++jj)
#pragma unroll
        for (int i = 0; i < 4; ++i)
            w[jj * 4 + i] = __hip_atomic_load(
                &Whh[(size_t)row * HH + wave * 128 + jj * 16 + q * 4 + i],
                __ATOMIC_RELAXED, __HIP_MEMORY_SCOPE_WORKGROUP);

    // out-projection weights pinned: wl[u*4+i] pairs with
    // hs[wave*128 + (2jp+u)*16 + q*4 + i]
    float wl[8];
#pragma unroll
    for (int u = 0; u < 2; ++u)
#pragma unroll
        for (int i = 0; i < 4; ++i)
            wl[u * 4 + i] = __hip_atomic_load(
                &Wlin[(size_t)(b * 4 + o) * HH + wave * 128 + (2 * jp + u) * 16 + q * 4 + i],
                __ATOMIC_RELAXED, __HIP_MEMORY_SCOPE_WORKGROUP);

    const bool is_writer = (wave == 0) && (lane < RPB);
    const float bias  = is_writer ? bhh[b * RPB + lane] : 0.f;
    const float obias = (lane < 4) ? blin[b * 4 + lane] : 0.f;

    __shared__ float hs[HH];               // staged h (fp32), wave-private
    __shared__ float partial[16][68];      // [k-chunk wave][q*17 + r]
    __shared__ float outp[2][64];          // [t parity][wave*4 + o]

    int last_c = -1;

    for (int t = 0; t < TT; ++t) {
        // xp gating + load: only writer lanes; poll only at chunk boundary
        float xpv = 0.f;
        if (is_writer) {
            const int c = t >> 6;   // t / CHUNK_T
            if (c != last_c) {
                while (__hip_atomic_load(&chunk_done[c],
                        __ATOMIC_RELAXED, __HIP_MEMORY_SCOPE_AGENT) < NHT) {}
                last_c = c;
            }
            xpv = __hip_atomic_load(&xp[(size_t)t * HH + b * RPB + lane],
                                    __ATOMIC_RELAXED, __HIP_MEMORY_SCOPE_AGENT);
        }

        // stage MY wave's 128-float chunk: ONE tagged word per lane
        if (t == 0) {
            float2 hv; hv.x = h0[s0]; hv.y = h0[s0 + 1];
            *(float2*)&hs[s0] = hv;
        } else {
            const unsigned int want = (unsigned int)t;
            const unsigned long long* mb = mbox + (size_t)(t & 1) * MBW;
            unsigned long long v;
            do {
                v = __hip_atomic_load(&mb[m0],
                    __ATOMIC_RELAXED, __HIP_MEMORY_SCOPE_AGENT);
            } while ((unsigned int)(v >> 32) != want);
            half2v hp = __builtin_bit_cast(half2v, (unsigned int)v);
            float2 hv;
            hv.x = (float)hp[0];
            hv.y = (float)hp[1];
            *(float2*)&hs[s0] = hv;   // same-wave write->read: lgkmcnt only
        }

        // matvec partial: 8 broadcast ds_read_b128 + 32 FMA (interleaved map)
        const float* hk = &hs[wave * 128 + q * 4];
        float p = 0.f;
#pragma unroll
        for (int jj = 0; jj < 8; ++jj) {
            float4 h4 = *(const float4*)&hk[jj * 16];
            p += w[jj * 4 + 0] * h4.x + w[jj * 4 + 1] * h4.y
               + w[jj * 4 + 2] * h4.z + w[jj * 4 + 3] * h4.w;
        }
        partial[wave][q * 17 + r] = p;

        // out-projection partial for out[t-1] (staged hs = h_{t-1}):
        // 2 re-reads of my jj-pair + 8 FMA + 4 folds; lanes 0..3 write outp
        {
            float4 ha = *(const float4*)&hk[(2 * jp) * 16];
            float4 hb = *(const float4*)&hk[(2 * jp + 1) * 16];
            float po = wl[0] * ha.x + wl[1] * ha.y + wl[2] * ha.z + wl[3] * ha.w
                     + wl[4] * hb.x + wl[5] * hb.y + wl[6] * hb.z + wl[7] * hb.w;
            po += __shfl_xor(po, 4, 64);
            po += __shfl_xor(po, 8, 64);
            po += __shfl_xor(po, 16, 64);
            po += __shfl_xor(po, 32, 64);
            if (lane < 4) outp[t & 1][wave * 4 + lane] = po;
        }
        __syncthreads();   // (B) the ONLY barrier per step

        if (wave == 0) {
            // secure outp value BEFORE publish (closes overwrite race; folds later)
            float ov = outp[t & 1][lane];
            // h-reduce: lane l: row=l&15, qq=l>>4; sum over 16 k-chunk waves
            const int idx = (lane >> 4) * 17 + (lane & 15);
            float s = 0.f;
#pragma unroll
            for (int g = 0; g < 16; ++g) s += partial[g][idx];
            s += __shfl_xor(s, 16, 64);   // fold qq bit 0
            s += __shfl_xor(s, 32, 64);   // fold qq bit 1
            float z = xpv + bias + s;
            z = fminf(15.f, fmaxf(-15.f, z));
            float e = __builtin_exp2f(z * 2.885390082f);
            float hv = (e - 1.f) * __builtin_amdgcn_rcpf(e + 1.f);
            // pack rows 2i,2i+1 into lane i (i<8): one 64B-line publish FIRST
            float ha = __shfl(hv, 2 * lane, 64);
            float hb = __shfl(hv, 2 * lane + 1, 64);
            if (lane < 8) {
                half2v pk2 = __builtin_amdgcn_cvt_pkrtz(ha, hb);
                unsigned int pb = __builtin_bit_cast(unsigned int, pk2);
                unsigned long long word =
                    ((unsigned long long)(unsigned int)(t + 1) << 32) |
                    (unsigned long long)pb;
                __hip_atomic_store(&mbox[(size_t)((t + 1) & 1) * MBW + b * 8 + lane],
                                   word, __ATOMIC_RELAXED, __HIP_MEMORY_SCOPE_AGENT);
            }
            // out[t-1] fold + store: entirely AFTER publish (off critical path)
            ov += __shfl_xor(ov, 4, 64);
            ov += __shfl_xor(ov, 8, 64);
            ov += __shfl_xor(ov, 16, 64);
            ov += __shfl_xor(ov, 32, 64);
            if ((lane < 4) && (t > 0))
                out[(size_t)(t - 1) * OO + b * 4 + lane] = ov + obias;
        }
        // partial[w]/outp overwrite for t+1/t+2 gated by wave w's next poll,
        // which requires this block's wave-0 publish (after the reads above).
    }

    // ---- epilogue: out[TT-1] from h_{TT-1} (published with tag TT) ----
    {
        const unsigned int want = (unsigned int)TT;
        const unsigned long long* mb = mbox + (size_t)(TT & 1) * MBW;
        unsigned long long v;
        do {
            v = __hip_atomic_load(&mb[m0],
                __ATOMIC_RELAXED, __HIP_MEMORY_SCOPE_AGENT);
        } while ((unsigned int)(v >> 32) != want);
        half2v hp = __builtin_bit_cast(half2v, (unsigned int)v);
        float2 hv;
        hv.x = (float)hp[0];
        hv.y = (float)hp[1];
        *(float2*)&hs[s0] = hv;

        const float* hk = &hs[wave * 128 + q * 4];
        float4 ha = *(const float4*)&hk[(2 * jp) * 16];
        float4 hb = *(const float4*)&hk[(2 * jp + 1) * 16];
        float po = wl[0] * ha.x + wl[1] * ha.y + wl[2] * ha.z + wl[3] * ha.w
                 + wl[4] * hb.x + wl[5] * hb.y + wl[6] * hb.z + wl[7] * hb.w;
        po += __shfl_xor(po, 4, 64);
        po += __shfl_xor(po, 8, 64);
        po += __shfl_xor(po, 16, 64);
        po += __shfl_xor(po, 32, 64);
        if (lane < 4) outp[0][wave * 4 + lane] = po;
        __syncthreads();

        if (wave == 0) {
            float ov = outp[0][lane];
            ov += __shfl_xor(ov, 4, 64);
            ov += __shfl_xor(ov, 8, 64);
            ov += __shfl_xor(ov, 16, 64);
            ov += __shfl_xor(ov, 32, 64);
            if (lane < 4)
                out[(size_t)(TT - 1) * OO + b * 4 + lane] = ov + obias;
        }
    }
}

// ---------------------------------------------------------------------------
extern "C" void kernel_launch(void* const* d_in, const int* in_sizes, int n_in,
                              void* d_out, int out_size, void* d_ws, size_t ws_size,
                              hipStream_t stream)
{
    const float* x     = (const float*)d_in[0];  // (T,1,H)
    const float* W_ih  = (const float*)d_in[1];  // (H,H)
    const float* W_hh  = (const float*)d_in[2];  // (H,H)
    const float* b_ih  = (const float*)d_in[3];  // (H)
    const float* b_hh  = (const float*)d_in[4];  // (H)
    const float* W_lin = (const float*)d_in[5];  // (O,H)
    const float* b_lin = (const float*)d_in[6];  // (O)
    const float* h0    = (const float*)d_in[7];  // (1,1,H)
    float* out = (float*)d_out;                  // (T,1,O)

    char* ws = (char*)d_ws;
    float* xp = (float*)ws;                                          // 32 MB
    unsigned long long* mbox =
        (unsigned long long*)(ws + (size_t)TT * HH * 4);             // 16 KB
    int* chunk_done =
        (int*)(ws + (size_t)TT * HH * 4 + 2 * MBW * 8);              // 256 B

    // chunk counters must start at 0 (ws arrives poisoned); mailbox needs
    // no init (t==0 reads h0; poisoned tag never equals a wanted tag).
    hipMemsetAsync(chunk_done, 0, NCHUNK * sizeof(int), stream);

    // single dispatch: phase 1 (workers) + phase 2 (scan) + phase 3 (in-scan)
    rnn_fused<<<2 * NB, 1024, 0, stream>>>(
        x, W_ih, b_ih, W_hh, b_hh, h0, W_lin, b_lin, xp, out, mbox, chunk_done);
}